// Round 1
// baseline (1879.318 us; speedup 1.0000x reference)
//
#include <hip/hip_runtime.h>

#define NN 100000   // nodes
#define NE 1600000  // edges
#define IN_CH 41
#define EDIM 8
#define H 64
#define GNUM 256
#define ATOM 21
#define EPSV 1e-5f

__device__ __forceinline__ float wave_reduce_sum(float v) {
#pragma unroll
    for (int o = 32; o > 0; o >>= 1) v += __shfl_xor(v, o, 64);
    return v;
}

// ---------------- encoder: h = select(mask, protMLP(x), ligMLP(x)) ----------
__global__ __launch_bounds__(256) void encoder_kernel(
    const float* __restrict__ x,
    const float* __restrict__ ligW1, const float* __restrict__ ligb1,
    const float* __restrict__ ligW2, const float* __restrict__ ligb2,
    const float* __restrict__ protW1, const float* __restrict__ protb1,
    const float* __restrict__ protW2, const float* __restrict__ protb2,
    float* __restrict__ h)
{
    const int lane = threadIdx.x & 63;
    const int node = blockIdx.x * 4 + (threadIdx.x >> 6);
    if (node >= NN) return;

    // lane d (<41) holds x[node][d]
    float xv = (lane < IN_CH) ? x[node * IN_CH + lane] : 0.0f;
    // residue-part mask: sum |x[:,21:41]| > 1e-6
    float m = (lane >= ATOM && lane < IN_CH) ? fabsf(xv) : 0.0f;
    m = wave_reduce_sum(m);
    const bool prot = m > 1e-6f;
    const float* W1 = prot ? protW1 : ligW1;
    const float* b1 = prot ? protb1 : ligb1;
    const float* W2 = prot ? protW2 : ligW2;
    const float* b2 = prot ? protb2 : ligb2;

    float acc = b1[lane];
#pragma unroll
    for (int d = 0; d < IN_CH; ++d)
        acc = fmaf(__shfl(xv, d, 64), W1[d * H + lane], acc);
    float h1 = fmaxf(acc, 0.0f);

    float acc2 = b2[lane];
#pragma unroll
    for (int d = 0; d < H; ++d)
        acc2 = fmaf(__shfl(h1, d, 64), W2[d * H + lane], acc2);
    h[node * H + lane] = fmaxf(acc2, 0.0f);
}

// ---------------- z = h (copy, so edge atomics produce z = h + aggr) --------
__global__ __launch_bounds__(256) void copy_kernel(
    const float4* __restrict__ src, float4* __restrict__ dst, int n4)
{
    int i = blockIdx.x * blockDim.x + threadIdx.x;
    if (i < n4) dst[i] = src[i];
}

// ---------------- per-graph node ranges (batch is sorted) -------------------
__global__ void bounds_kernel(const int* __restrict__ batch, int* __restrict__ start)
{
    int g = blockIdx.x * blockDim.x + threadIdx.x;
    if (g > GNUM) return;
    int lo = 0, hi = NN;
    while (lo < hi) {
        int mid = (lo + hi) >> 1;
        if (batch[mid] < g) lo = mid + 1; else hi = mid;
    }
    start[g] = lo;  // first node with batch >= g ; start[GNUM] == NN
}

// ---------------- edge messages: z[dst] += relu(h[src] + ea @ We + be) ------
__global__ __launch_bounds__(256) void edge_kernel(
    const int* __restrict__ ei, const float* __restrict__ ea,
    const float* __restrict__ We, const float* __restrict__ be,
    const float* __restrict__ h, float* __restrict__ z)
{
    const int lane = threadIdx.x & 63;
    const int e = blockIdx.x * 4 + (threadIdx.x >> 6);
    if (e >= NE) return;
    const int src = ei[e];
    const int dst = ei[NE + e];
    float ev = (lane < EDIM) ? ea[e * EDIM + lane] : 0.0f;
    float acc = be[lane];
#pragma unroll
    for (int d = 0; d < EDIM; ++d)
        acc = fmaf(__shfl(ev, d, 64), We[d * H + lane], acc);
    float msg = fmaxf(h[src * H + lane] + acc, 0.0f);
    unsafeAtomicAdd(&z[dst * H + lane], msg);
}

// ---------------- node MLP: h = relu(z@W1+b1)@W2+b2 (no outer relu) ---------
__global__ __launch_bounds__(256) void node_mlp_kernel(
    const float* __restrict__ z,
    const float* __restrict__ W1, const float* __restrict__ b1,
    const float* __restrict__ W2, const float* __restrict__ b2,
    float* __restrict__ h)
{
    const int lane = threadIdx.x & 63;
    const int node = blockIdx.x * 4 + (threadIdx.x >> 6);
    if (node >= NN) return;
    float zv = z[node * H + lane];
    float acc = b1[lane];
#pragma unroll
    for (int d = 0; d < H; ++d)
        acc = fmaf(__shfl(zv, d, 64), W1[d * H + lane], acc);
    float t = fmaxf(acc, 0.0f);
    float acc2 = b2[lane];
#pragma unroll
    for (int d = 0; d < H; ++d)
        acc2 = fmaf(__shfl(t, d, 64), W2[d * H + lane], acc2);
    h[node * H + lane] = acc2;
}

// ---------------- GraphNorm + relu, in place, one block per graph -----------
__global__ __launch_bounds__(256) void graphnorm_kernel(
    float* __restrict__ h, const int* __restrict__ start,
    const float* __restrict__ w, const float* __restrict__ b,
    const float* __restrict__ a)
{
    __shared__ float red1[4][H], red2[4][H];
    __shared__ float amean_s[H], rstd_s[H];
    const int g = blockIdx.x;
    const int lane = threadIdx.x & 63;
    const int wv = threadIdx.x >> 6;
    const int s = start[g], e = start[g + 1];

    float s1 = 0.f, s2 = 0.f;
    for (int i = s + wv; i < e; i += 4) {
        float v = h[i * H + lane];
        s1 += v; s2 += v * v;
    }
    red1[wv][lane] = s1; red2[wv][lane] = s2;
    __syncthreads();
    if (threadIdx.x < H) {
        float t1 = red1[0][lane] + red1[1][lane] + red1[2][lane] + red1[3][lane];
        float t2 = red2[0][lane] + red2[1][lane] + red2[2][lane] + red2[3][lane];
        float cnt = fmaxf((float)(e - s), 1.0f);
        float mean = t1 / cnt;
        float alpha = a[lane];
        // var of (h - alpha*mean): E[h^2] - (2a - a^2) mean^2
        float var = t2 / cnt - (2.0f * alpha - alpha * alpha) * mean * mean;
        var = fmaxf(var, 0.0f);
        amean_s[lane] = alpha * mean;
        rstd_s[lane] = rsqrtf(var + EPSV);
    }
    __syncthreads();
    const float am = amean_s[lane], rstd = rstd_s[lane];
    const float ww = w[lane], bb = b[lane];
    for (int i = s + wv; i < e; i += 4) {
        float v = (h[i * H + lane] - am) * rstd * ww + bb;
        h[i * H + lane] = fmaxf(v, 0.0f);
    }
}

// ---------------- pool + readout: out[g] ------------------------------------
__global__ __launch_bounds__(256) void final_kernel(
    const float* __restrict__ h, const int* __restrict__ start,
    const float* __restrict__ W1, const float* __restrict__ b1,
    const float* __restrict__ W2, const float* __restrict__ b2,
    float* __restrict__ out)
{
    __shared__ float red[4][H];
    __shared__ float g_s[H];
    const int g = blockIdx.x;
    const int lane = threadIdx.x & 63;
    const int wv = threadIdx.x >> 6;
    const int s = start[g], e = start[g + 1];

    float s1 = 0.f;
    for (int i = s + wv; i < e; i += 4) s1 += h[i * H + lane];
    red[wv][lane] = s1;
    __syncthreads();
    if (threadIdx.x < H)
        g_s[lane] = red[0][lane] + red[1][lane] + red[2][lane] + red[3][lane];
    __syncthreads();
    if (threadIdx.x < H) {
        float acc = b1[lane];
#pragma unroll
        for (int d = 0; d < H; ++d)
            acc = fmaf(g_s[d], W1[d * H + lane], acc);
        float r = fmaxf(acc, 0.0f);
        float v = r * W2[lane];
        v = wave_reduce_sum(v);
        if (lane == 0) out[g] = v + b2[0];
    }
}

extern "C" void kernel_launch(void* const* d_in, const int* in_sizes, int n_in,
                              void* d_out, int out_size, void* d_ws, size_t ws_size,
                              hipStream_t stream)
{
    const float* x      = (const float*)d_in[0];
    const int*   ei     = (const int*)  d_in[1];
    const float* ea     = (const float*)d_in[2];
    const int*   batch  = (const int*)  d_in[3];
    const float* ligW1  = (const float*)d_in[4];
    const float* ligb1  = (const float*)d_in[5];
    const float* ligW2  = (const float*)d_in[6];
    const float* ligb2  = (const float*)d_in[7];
    const float* protW1 = (const float*)d_in[8];
    const float* protb1 = (const float*)d_in[9];
    const float* protW2 = (const float*)d_in[10];
    const float* protb2 = (const float*)d_in[11];
    const float* convWe = (const float*)d_in[12];
    const float* convbe = (const float*)d_in[13];
    const float* convW1 = (const float*)d_in[14];
    const float* convb1 = (const float*)d_in[15];
    const float* convW2 = (const float*)d_in[16];
    const float* convb2 = (const float*)d_in[17];
    const float* normw  = (const float*)d_in[18];
    const float* normb  = (const float*)d_in[19];
    const float* norma  = (const float*)d_in[20];
    const float* outW1  = (const float*)d_in[21];
    const float* outb1  = (const float*)d_in[22];
    const float* outW2  = (const float*)d_in[23];
    const float* outb2  = (const float*)d_in[24];

    float* out = (float*)d_out;

    float* h = (float*)d_ws;                  // NN*H floats
    float* z = h + (size_t)NN * H;            // NN*H floats
    int* start = (int*)(z + (size_t)NN * H);  // GNUM+1 ints

    encoder_kernel<<<(NN + 3) / 4, 256, 0, stream>>>(
        x, ligW1, ligb1, ligW2, ligb2, protW1, protb1, protW2, protb2, h);
    bounds_kernel<<<2, 256, 0, stream>>>(batch, start);

    const int n4 = NN * H / 4;
    for (int l = 0; l < 3; ++l) {
        copy_kernel<<<(n4 + 255) / 256, 256, 0, stream>>>(
            (const float4*)h, (float4*)z, n4);
        edge_kernel<<<(NE + 3) / 4, 256, 0, stream>>>(
            ei, ea, convWe + (size_t)l * EDIM * H, convbe + (size_t)l * H, h, z);
        node_mlp_kernel<<<(NN + 3) / 4, 256, 0, stream>>>(
            z, convW1 + (size_t)l * H * H, convb1 + (size_t)l * H,
            convW2 + (size_t)l * H * H, convb2 + (size_t)l * H, h);
        graphnorm_kernel<<<GNUM, 256, 0, stream>>>(
            h, start, normw + (size_t)l * H, normb + (size_t)l * H, norma + (size_t)l * H);
    }
    final_kernel<<<GNUM, 256, 0, stream>>>(h, start, outW1, outb1, outW2, outb2, out);
}

// Round 2
// 1677.424 us; speedup vs baseline: 1.1204x; 1.1204x over previous
//
#include <hip/hip_runtime.h>

#define NN 100000   // nodes
#define NE 1600000  // edges
#define IN_CH 41
#define EDIM 8
#define H 64
#define GNUM 256
#define ATOM 21
#define EPSV 1e-5f

#define NBLK_SCAN ((NN + 255) / 256)   // 391

__device__ __forceinline__ float wave_reduce_sum(float v) {
#pragma unroll
    for (int o = 32; o > 0; o >>= 1) v += __shfl_xor(v, o, 64);
    return v;
}

// ---------------- encoder: h = select(mask, protMLP(x), ligMLP(x)) ----------
__global__ __launch_bounds__(256) void encoder_kernel(
    const float* __restrict__ x,
    const float* __restrict__ ligW1, const float* __restrict__ ligb1,
    const float* __restrict__ ligW2, const float* __restrict__ ligb2,
    const float* __restrict__ protW1, const float* __restrict__ protb1,
    const float* __restrict__ protW2, const float* __restrict__ protb2,
    float* __restrict__ h)
{
    const int lane = threadIdx.x & 63;
    const int node = blockIdx.x * 4 + (threadIdx.x >> 6);
    if (node >= NN) return;

    float xv = (lane < IN_CH) ? x[node * IN_CH + lane] : 0.0f;
    float m = (lane >= ATOM && lane < IN_CH) ? fabsf(xv) : 0.0f;
    m = wave_reduce_sum(m);
    const bool prot = m > 1e-6f;
    const float* W1 = prot ? protW1 : ligW1;
    const float* b1 = prot ? protb1 : ligb1;
    const float* W2 = prot ? protW2 : ligW2;
    const float* b2 = prot ? protb2 : ligb2;

    float acc = b1[lane];
#pragma unroll
    for (int d = 0; d < IN_CH; ++d)
        acc = fmaf(__shfl(xv, d, 64), W1[d * H + lane], acc);
    float h1 = fmaxf(acc, 0.0f);

    float acc2 = b2[lane];
#pragma unroll
    for (int d = 0; d < H; ++d)
        acc2 = fmaf(__shfl(h1, d, 64), W2[d * H + lane], acc2);
    h[node * H + lane] = fmaxf(acc2, 0.0f);
}

// ---------------- per-graph node ranges (batch is sorted) -------------------
__global__ void bounds_kernel(const int* __restrict__ batch, int* __restrict__ start)
{
    int g = blockIdx.x * blockDim.x + threadIdx.x;
    if (g > GNUM) return;
    int lo = 0, hi = NN;
    while (lo < hi) {
        int mid = (lo + hi) >> 1;
        if (batch[mid] < g) lo = mid + 1; else hi = mid;
    }
    start[g] = lo;
}

// ---------------- CSR build ------------------------------------------------
__global__ __launch_bounds__(256) void zero_deg_kernel(int* __restrict__ deg)
{
    int i = blockIdx.x * blockDim.x + threadIdx.x;
    if (i < NN) deg[i] = 0;
}

__global__ __launch_bounds__(256) void hist_kernel(
    const int* __restrict__ ei, int* __restrict__ deg)
{
    int e = blockIdx.x * blockDim.x + threadIdx.x;
    if (e < NE) atomicAdd(&deg[ei[NE + e]], 1);
}

// block-level exclusive scan of deg -> row_start(partial), bsum[b]=block total
__global__ __launch_bounds__(256) void scan_a_kernel(
    const int* __restrict__ deg, int* __restrict__ row_start, int* __restrict__ bsum)
{
    __shared__ int s[256];
    const int t = threadIdx.x;
    const int idx = blockIdx.x * 256 + t;
    int v = (idx < NN) ? deg[idx] : 0;
    s[t] = v;
    __syncthreads();
#pragma unroll
    for (int off = 1; off < 256; off <<= 1) {
        int tmp = (t >= off) ? s[t - off] : 0;
        __syncthreads();
        s[t] += tmp;
        __syncthreads();
    }
    if (idx < NN) row_start[idx] = s[t] - v;  // exclusive
    if (t == 255) bsum[blockIdx.x] = s[255];
}

__global__ __launch_bounds__(512) void scan_b_kernel(int* __restrict__ bsum)
{
    __shared__ int s[512];
    const int t = threadIdx.x;
    int v = (t < NBLK_SCAN) ? bsum[t] : 0;
    s[t] = v;
    __syncthreads();
#pragma unroll
    for (int off = 1; off < 512; off <<= 1) {
        int tmp = (t >= off) ? s[t - off] : 0;
        __syncthreads();
        s[t] += tmp;
        __syncthreads();
    }
    if (t < NBLK_SCAN) bsum[t] = s[t] - v;  // exclusive
}

__global__ __launch_bounds__(256) void scan_c_kernel(
    int* __restrict__ row_start, const int* __restrict__ bsum, int* __restrict__ cursor)
{
    const int idx = blockIdx.x * 256 + threadIdx.x;
    if (idx < NN) {
        int rs = row_start[idx] + bsum[blockIdx.x];
        row_start[idx] = rs;
        cursor[idx] = rs;
    } else if (idx == NN) {
        row_start[NN] = NE;
    }
}

__global__ __launch_bounds__(256) void fill_kernel(
    const int* __restrict__ ei, int* __restrict__ cursor,
    int* __restrict__ perm_src, int* __restrict__ perm_eid)
{
    int e = blockIdx.x * blockDim.x + threadIdx.x;
    if (e >= NE) return;
    int dst = ei[NE + e];
    int pos = atomicAdd(&cursor[dst], 1);
    perm_src[pos] = ei[e];
    perm_eid[pos] = e;
}

// ---------------- aggregation: z[n] = h[n] + sum_{e->n} relu(h[src]+lin(ea))
__global__ __launch_bounds__(256) void aggr_kernel(
    const int* __restrict__ row_start,
    const int* __restrict__ perm_src, const int* __restrict__ perm_eid,
    const float* __restrict__ ea,
    const float* __restrict__ We, const float* __restrict__ be,
    const float* __restrict__ h, float* __restrict__ z)
{
    const int lane = threadIdx.x & 63;
    const int node = blockIdx.x * 4 + (threadIdx.x >> 6);
    if (node >= NN) return;

    float we_r[EDIM];
#pragma unroll
    for (int d = 0; d < EDIM; ++d) we_r[d] = We[d * H + lane];
    const float be_r = be[lane];

    float acc = h[node * H + lane];
    const int s = row_start[node];
    const int e = row_start[node + 1];
    for (int k = s; k < e; ++k) {
        const int src = perm_src[k];
        const int eid = perm_eid[k];
        float evv = (lane < EDIM) ? ea[eid * EDIM + lane] : 0.0f;
        float hv = h[src * H + lane];
        float msg = be_r;
#pragma unroll
        for (int d = 0; d < EDIM; ++d)
            msg = fmaf(__shfl(evv, d, 64), we_r[d], msg);
        acc += fmaxf(hv + msg, 0.0f);
    }
    z[node * H + lane] = acc;
}

// ---------------- node MLP: h = relu(z@W1+b1)@W2+b2 -------------------------
__global__ __launch_bounds__(256) void node_mlp_kernel(
    const float* __restrict__ z,
    const float* __restrict__ W1, const float* __restrict__ b1,
    const float* __restrict__ W2, const float* __restrict__ b2,
    float* __restrict__ h)
{
    const int lane = threadIdx.x & 63;
    const int node = blockIdx.x * 4 + (threadIdx.x >> 6);
    if (node >= NN) return;
    float zv = z[node * H + lane];
    float acc = b1[lane];
#pragma unroll
    for (int d = 0; d < H; ++d)
        acc = fmaf(__shfl(zv, d, 64), W1[d * H + lane], acc);
    float t = fmaxf(acc, 0.0f);
    float acc2 = b2[lane];
#pragma unroll
    for (int d = 0; d < H; ++d)
        acc2 = fmaf(__shfl(t, d, 64), W2[d * H + lane], acc2);
    h[node * H + lane] = acc2;
}

// ---------------- GraphNorm + relu, in place, one block per graph -----------
__global__ __launch_bounds__(256) void graphnorm_kernel(
    float* __restrict__ h, const int* __restrict__ start,
    const float* __restrict__ w, const float* __restrict__ b,
    const float* __restrict__ a)
{
    __shared__ float red1[4][H], red2[4][H];
    __shared__ float amean_s[H], rstd_s[H];
    const int g = blockIdx.x;
    const int lane = threadIdx.x & 63;
    const int wv = threadIdx.x >> 6;
    const int s = start[g], e = start[g + 1];

    float s1 = 0.f, s2 = 0.f;
    for (int i = s + wv; i < e; i += 4) {
        float v = h[i * H + lane];
        s1 += v; s2 += v * v;
    }
    red1[wv][lane] = s1; red2[wv][lane] = s2;
    __syncthreads();
    if (threadIdx.x < H) {
        float t1 = red1[0][lane] + red1[1][lane] + red1[2][lane] + red1[3][lane];
        float t2 = red2[0][lane] + red2[1][lane] + red2[2][lane] + red2[3][lane];
        float cnt = fmaxf((float)(e - s), 1.0f);
        float mean = t1 / cnt;
        float alpha = a[lane];
        float var = t2 / cnt - (2.0f * alpha - alpha * alpha) * mean * mean;
        var = fmaxf(var, 0.0f);
        amean_s[lane] = alpha * mean;
        rstd_s[lane] = rsqrtf(var + EPSV);
    }
    __syncthreads();
    const float am = amean_s[lane], rstd = rstd_s[lane];
    const float ww = w[lane], bb = b[lane];
    for (int i = s + wv; i < e; i += 4) {
        float v = (h[i * H + lane] - am) * rstd * ww + bb;
        h[i * H + lane] = fmaxf(v, 0.0f);
    }
}

// ---------------- pool + readout: out[g] ------------------------------------
__global__ __launch_bounds__(256) void final_kernel(
    const float* __restrict__ h, const int* __restrict__ start,
    const float* __restrict__ W1, const float* __restrict__ b1,
    const float* __restrict__ W2, const float* __restrict__ b2,
    float* __restrict__ out)
{
    __shared__ float red[4][H];
    __shared__ float g_s[H];
    const int g = blockIdx.x;
    const int lane = threadIdx.x & 63;
    const int wv = threadIdx.x >> 6;
    const int s = start[g], e = start[g + 1];

    float s1 = 0.f;
    for (int i = s + wv; i < e; i += 4) s1 += h[i * H + lane];
    red[wv][lane] = s1;
    __syncthreads();
    if (threadIdx.x < H)
        g_s[lane] = red[0][lane] + red[1][lane] + red[2][lane] + red[3][lane];
    __syncthreads();
    if (threadIdx.x < H) {
        float acc = b1[lane];
#pragma unroll
        for (int d = 0; d < H; ++d)
            acc = fmaf(g_s[d], W1[d * H + lane], acc);
        float r = fmaxf(acc, 0.0f);
        float v = r * W2[lane];
        v = wave_reduce_sum(v);
        if (lane == 0) out[g] = v + b2[0];
    }
}

extern "C" void kernel_launch(void* const* d_in, const int* in_sizes, int n_in,
                              void* d_out, int out_size, void* d_ws, size_t ws_size,
                              hipStream_t stream)
{
    const float* x      = (const float*)d_in[0];
    const int*   ei     = (const int*)  d_in[1];
    const float* ea     = (const float*)d_in[2];
    const int*   batch  = (const int*)  d_in[3];
    const float* ligW1  = (const float*)d_in[4];
    const float* ligb1  = (const float*)d_in[5];
    const float* ligW2  = (const float*)d_in[6];
    const float* ligb2  = (const float*)d_in[7];
    const float* protW1 = (const float*)d_in[8];
    const float* protb1 = (const float*)d_in[9];
    const float* protW2 = (const float*)d_in[10];
    const float* protb2 = (const float*)d_in[11];
    const float* convWe = (const float*)d_in[12];
    const float* convbe = (const float*)d_in[13];
    const float* convW1 = (const float*)d_in[14];
    const float* convb1 = (const float*)d_in[15];
    const float* convW2 = (const float*)d_in[16];
    const float* convb2 = (const float*)d_in[17];
    const float* normw  = (const float*)d_in[18];
    const float* normb  = (const float*)d_in[19];
    const float* norma  = (const float*)d_in[20];
    const float* outW1  = (const float*)d_in[21];
    const float* outb1  = (const float*)d_in[22];
    const float* outW2  = (const float*)d_in[23];
    const float* outb2  = (const float*)d_in[24];

    float* out = (float*)d_out;

    // workspace layout (4-byte elements)
    float* h         = (float*)d_ws;                    // NN*H
    float* z         = h + (size_t)NN * H;              // NN*H
    int*   row_start = (int*)(z + (size_t)NN * H);      // NN+1
    int*   cursor    = row_start + (NN + 1);            // NN
    int*   deg       = cursor + NN;                     // NN
    int*   bsum      = deg + NN;                        // 512
    int*   perm_src  = bsum + 512;                      // NE
    int*   perm_eid  = perm_src + NE;                   // NE
    int*   start     = perm_eid + NE;                   // GNUM+1

    encoder_kernel<<<(NN + 3) / 4, 256, 0, stream>>>(
        x, ligW1, ligb1, ligW2, ligb2, protW1, protb1, protW2, protb2, h);
    bounds_kernel<<<2, 256, 0, stream>>>(batch, start);

    // ---- CSR build (once per launch) ----
    zero_deg_kernel<<<(NN + 255) / 256, 256, 0, stream>>>(deg);
    hist_kernel<<<(NE + 255) / 256, 256, 0, stream>>>(ei, deg);
    scan_a_kernel<<<NBLK_SCAN, 256, 0, stream>>>(deg, row_start, bsum);
    scan_b_kernel<<<1, 512, 0, stream>>>(bsum);
    scan_c_kernel<<<NBLK_SCAN, 256, 0, stream>>>(row_start, bsum, cursor);
    fill_kernel<<<(NE + 255) / 256, 256, 0, stream>>>(ei, cursor, perm_src, perm_eid);

    for (int l = 0; l < 3; ++l) {
        aggr_kernel<<<(NN + 3) / 4, 256, 0, stream>>>(
            row_start, perm_src, perm_eid, ea,
            convWe + (size_t)l * EDIM * H, convbe + (size_t)l * H, h, z);
        node_mlp_kernel<<<(NN + 3) / 4, 256, 0, stream>>>(
            z, convW1 + (size_t)l * H * H, convb1 + (size_t)l * H,
            convW2 + (size_t)l * H * H, convb2 + (size_t)l * H, h);
        graphnorm_kernel<<<GNUM, 256, 0, stream>>>(
            h, start, normw + (size_t)l * H, normb + (size_t)l * H, norma + (size_t)l * H);
    }
    final_kernel<<<GNUM, 256, 0, stream>>>(h, start, outW1, outb1, outW2, outb2, out);
}

// Round 3
// 1518.095 us; speedup vs baseline: 1.2379x; 1.1050x over previous
//
#include <hip/hip_runtime.h>

#define NN 100000   // nodes
#define NE 1600000  // edges
#define IN_CH 41
#define EDIM 8
#define H 64
#define GNUM 256
#define ATOM 21
#define EPSV 1e-5f

#define NBLK_SCAN ((NN + 255) / 256)   // 391

__device__ __forceinline__ float wave_reduce_sum(float v) {
#pragma unroll
    for (int o = 32; o > 0; o >>= 1) v += __shfl_xor(v, o, 64);
    return v;
}

// ---------------- encoder: h = select(mask, protMLP(x), ligMLP(x)) ----------
__global__ __launch_bounds__(256) void encoder_kernel(
    const float* __restrict__ x,
    const float* __restrict__ ligW1, const float* __restrict__ ligb1,
    const float* __restrict__ ligW2, const float* __restrict__ ligb2,
    const float* __restrict__ protW1, const float* __restrict__ protb1,
    const float* __restrict__ protW2, const float* __restrict__ protb2,
    float* __restrict__ h)
{
    const int lane = threadIdx.x & 63;
    const int node = blockIdx.x * 4 + (threadIdx.x >> 6);
    if (node >= NN) return;

    float xv = (lane < IN_CH) ? x[node * IN_CH + lane] : 0.0f;
    float m = (lane >= ATOM && lane < IN_CH) ? fabsf(xv) : 0.0f;
    m = wave_reduce_sum(m);
    const bool prot = m > 1e-6f;
    const float* W1 = prot ? protW1 : ligW1;
    const float* b1 = prot ? protb1 : ligb1;
    const float* W2 = prot ? protW2 : ligW2;
    const float* b2 = prot ? protb2 : ligb2;

    float acc = b1[lane];
#pragma unroll
    for (int d = 0; d < IN_CH; ++d)
        acc = fmaf(__shfl(xv, d, 64), W1[d * H + lane], acc);
    float h1 = fmaxf(acc, 0.0f);

    float acc2 = b2[lane];
#pragma unroll
    for (int d = 0; d < H; ++d)
        acc2 = fmaf(__shfl(h1, d, 64), W2[d * H + lane], acc2);
    h[node * H + lane] = fmaxf(acc2, 0.0f);
}

// ---------------- per-graph node ranges (batch is sorted) -------------------
__global__ void bounds_kernel(const int* __restrict__ batch, int* __restrict__ start)
{
    int g = blockIdx.x * blockDim.x + threadIdx.x;
    if (g > GNUM) return;
    int lo = 0, hi = NN;
    while (lo < hi) {
        int mid = (lo + hi) >> 1;
        if (batch[mid] < g) lo = mid + 1; else hi = mid;
    }
    start[g] = lo;
}

// ---------------- CSR build ------------------------------------------------
__global__ __launch_bounds__(256) void hist_kernel(
    const int* __restrict__ ei, int* __restrict__ deg)
{
    int e = blockIdx.x * blockDim.x + threadIdx.x;
    if (e < NE) atomicAdd(&deg[ei[NE + e]], 1);
}

__global__ __launch_bounds__(256) void scan_a_kernel(
    const int* __restrict__ deg, int* __restrict__ row_start, int* __restrict__ bsum)
{
    __shared__ int s[256];
    const int t = threadIdx.x;
    const int idx = blockIdx.x * 256 + t;
    int v = (idx < NN) ? deg[idx] : 0;
    s[t] = v;
    __syncthreads();
#pragma unroll
    for (int off = 1; off < 256; off <<= 1) {
        int tmp = (t >= off) ? s[t - off] : 0;
        __syncthreads();
        s[t] += tmp;
        __syncthreads();
    }
    if (idx < NN) row_start[idx] = s[t] - v;  // exclusive
    if (t == 255) bsum[blockIdx.x] = s[255];
}

__global__ __launch_bounds__(512) void scan_b_kernel(int* __restrict__ bsum)
{
    __shared__ int s[512];
    const int t = threadIdx.x;
    int v = (t < NBLK_SCAN) ? bsum[t] : 0;
    s[t] = v;
    __syncthreads();
#pragma unroll
    for (int off = 1; off < 512; off <<= 1) {
        int tmp = (t >= off) ? s[t - off] : 0;
        __syncthreads();
        s[t] += tmp;
        __syncthreads();
    }
    if (t < NBLK_SCAN) bsum[t] = s[t] - v;  // exclusive
}

__global__ __launch_bounds__(256) void scan_c_kernel(
    int* __restrict__ row_start, const int* __restrict__ bsum, int* __restrict__ cursor)
{
    const int idx = blockIdx.x * 256 + threadIdx.x;
    if (idx < NN) {
        int rs = row_start[idx] + bsum[blockIdx.x];
        row_start[idx] = rs;
        cursor[idx] = rs;
    } else if (idx == NN) {
        row_start[NN] = NE;
    }
}

__global__ __launch_bounds__(256) void fill_kernel(
    const int* __restrict__ ei, int* __restrict__ cursor, int2* __restrict__ perm)
{
    int e = blockIdx.x * blockDim.x + threadIdx.x;
    if (e >= NE) return;
    int dst = ei[NE + e];
    int pos = atomicAdd(&cursor[dst], 1);
    perm[pos] = make_int2(ei[e], e);   // (src, edge_id)
}

// ---- aggregation: z[n] = h[n] + sum_{e->n} relu(h[src]+lin(ea)) ------------
// 8-edge batches: coalesced perm load into lanes 0..7, one ea load covering
// 8 edges x 8 channels, then 8 independent h-row gathers in flight.
__global__ __launch_bounds__(256) void aggr_kernel(
    const int* __restrict__ row_start,
    const int2* __restrict__ perm,
    const float* __restrict__ ea,
    const float* __restrict__ We, const float* __restrict__ be,
    const float* __restrict__ h, float* __restrict__ z)
{
    const int lane = threadIdx.x & 63;
    const int node = blockIdx.x * 4 + (threadIdx.x >> 6);
    if (node >= NN) return;

    float we_r[EDIM];
#pragma unroll
    for (int d = 0; d < EDIM; ++d) we_r[d] = We[d * H + lane];
    const float be_r = be[lane];

    const int s = row_start[node];
    const int e = row_start[node + 1];
    float acc = h[(size_t)node * H + lane];

    for (int k0 = s; k0 < e; k0 += 8) {
        const int nk = e - k0;                 // edges left (>=1)
        int idx = k0 + (lane & 7);
        if (idx > e - 1) idx = e - 1;          // clamp padding to valid edge
        const int2 pe = perm[idx];             // lanes 0..7 hold the 8 edges

        // each lane fetches (edge = lane>>3, channel = lane&7) of edge_attr
        const int eid_mine = __shfl(pe.y, lane >> 3, 64);
        const float eav = ea[(size_t)eid_mine * EDIM + (lane & 7)];

        float hv[8];
#pragma unroll
        for (int j = 0; j < 8; ++j) {
            const int src_j = __shfl(pe.x, j, 64);
            hv[j] = h[(size_t)src_j * H + lane];
        }
#pragma unroll
        for (int j = 0; j < 8; ++j) {
            if (j < nk) {
                float msg = be_r;
#pragma unroll
                for (int d = 0; d < EDIM; ++d)
                    msg = fmaf(__shfl(eav, j * 8 + d, 64), we_r[d], msg);
                acc += fmaxf(hv[j] + msg, 0.0f);
            }
        }
    }
    z[(size_t)node * H + lane] = acc;
}

// ---------------- node MLP: h = relu(z@W1+b1)@W2+b2 -------------------------
__global__ __launch_bounds__(256) void node_mlp_kernel(
    const float* __restrict__ z,
    const float* __restrict__ W1, const float* __restrict__ b1,
    const float* __restrict__ W2, const float* __restrict__ b2,
    float* __restrict__ h)
{
    const int lane = threadIdx.x & 63;
    const int node = blockIdx.x * 4 + (threadIdx.x >> 6);
    if (node >= NN) return;
    float zv = z[node * H + lane];
    float acc = b1[lane];
#pragma unroll
    for (int d = 0; d < H; ++d)
        acc = fmaf(__shfl(zv, d, 64), W1[d * H + lane], acc);
    float t = fmaxf(acc, 0.0f);
    float acc2 = b2[lane];
#pragma unroll
    for (int d = 0; d < H; ++d)
        acc2 = fmaf(__shfl(t, d, 64), W2[d * H + lane], acc2);
    h[node * H + lane] = acc2;
}

// ---------------- GraphNorm + relu, in place, one block per graph -----------
__global__ __launch_bounds__(256) void graphnorm_kernel(
    float* __restrict__ h, const int* __restrict__ start,
    const float* __restrict__ w, const float* __restrict__ b,
    const float* __restrict__ a)
{
    __shared__ float red1[4][H], red2[4][H];
    __shared__ float amean_s[H], rstd_s[H];
    const int g = blockIdx.x;
    const int lane = threadIdx.x & 63;
    const int wv = threadIdx.x >> 6;
    const int s = start[g], e = start[g + 1];

    float s1 = 0.f, s2 = 0.f;
    for (int i = s + wv; i < e; i += 4) {
        float v = h[i * H + lane];
        s1 += v; s2 += v * v;
    }
    red1[wv][lane] = s1; red2[wv][lane] = s2;
    __syncthreads();
    if (threadIdx.x < H) {
        float t1 = red1[0][lane] + red1[1][lane] + red1[2][lane] + red1[3][lane];
        float t2 = red2[0][lane] + red2[1][lane] + red2[2][lane] + red2[3][lane];
        float cnt = fmaxf((float)(e - s), 1.0f);
        float mean = t1 / cnt;
        float alpha = a[lane];
        float var = t2 / cnt - (2.0f * alpha - alpha * alpha) * mean * mean;
        var = fmaxf(var, 0.0f);
        amean_s[lane] = alpha * mean;
        rstd_s[lane] = rsqrtf(var + EPSV);
    }
    __syncthreads();
    const float am = amean_s[lane], rstd = rstd_s[lane];
    const float ww = w[lane], bb = b[lane];
    for (int i = s + wv; i < e; i += 4) {
        float v = (h[i * H + lane] - am) * rstd * ww + bb;
        h[i * H + lane] = fmaxf(v, 0.0f);
    }
}

// ---------------- pool + readout: out[g] ------------------------------------
__global__ __launch_bounds__(256) void final_kernel(
    const float* __restrict__ h, const int* __restrict__ start,
    const float* __restrict__ W1, const float* __restrict__ b1,
    const float* __restrict__ W2, const float* __restrict__ b2,
    float* __restrict__ out)
{
    __shared__ float red[4][H];
    __shared__ float g_s[H];
    const int g = blockIdx.x;
    const int lane = threadIdx.x & 63;
    const int wv = threadIdx.x >> 6;
    const int s = start[g], e = start[g + 1];

    float s1 = 0.f;
    for (int i = s + wv; i < e; i += 4) s1 += h[i * H + lane];
    red[wv][lane] = s1;
    __syncthreads();
    if (threadIdx.x < H)
        g_s[lane] = red[0][lane] + red[1][lane] + red[2][lane] + red[3][lane];
    __syncthreads();
    if (threadIdx.x < H) {
        float acc = b1[lane];
#pragma unroll
        for (int d = 0; d < H; ++d)
            acc = fmaf(g_s[d], W1[d * H + lane], acc);
        float r = fmaxf(acc, 0.0f);
        float v = r * W2[lane];
        v = wave_reduce_sum(v);
        if (lane == 0) out[g] = v + b2[0];
    }
}

extern "C" void kernel_launch(void* const* d_in, const int* in_sizes, int n_in,
                              void* d_out, int out_size, void* d_ws, size_t ws_size,
                              hipStream_t stream)
{
    const float* x      = (const float*)d_in[0];
    const int*   ei     = (const int*)  d_in[1];
    const float* ea     = (const float*)d_in[2];
    const int*   batch  = (const int*)  d_in[3];
    const float* ligW1  = (const float*)d_in[4];
    const float* ligb1  = (const float*)d_in[5];
    const float* ligW2  = (const float*)d_in[6];
    const float* ligb2  = (const float*)d_in[7];
    const float* protW1 = (const float*)d_in[8];
    const float* protb1 = (const float*)d_in[9];
    const float* protW2 = (const float*)d_in[10];
    const float* protb2 = (const float*)d_in[11];
    const float* convWe = (const float*)d_in[12];
    const float* convbe = (const float*)d_in[13];
    const float* convW1 = (const float*)d_in[14];
    const float* convb1 = (const float*)d_in[15];
    const float* convW2 = (const float*)d_in[16];
    const float* convb2 = (const float*)d_in[17];
    const float* normw  = (const float*)d_in[18];
    const float* normb  = (const float*)d_in[19];
    const float* norma  = (const float*)d_in[20];
    const float* outW1  = (const float*)d_in[21];
    const float* outb1  = (const float*)d_in[22];
    const float* outW2  = (const float*)d_in[23];
    const float* outb2  = (const float*)d_in[24];

    float* out = (float*)d_out;

    // workspace layout: perm (int2) right after h,z so it stays 8B-aligned
    float* h         = (float*)d_ws;                    // NN*H floats
    float* z         = h + (size_t)NN * H;              // NN*H floats
    int2*  perm      = (int2*)(z + (size_t)NN * H);     // NE int2
    int*   row_start = (int*)(perm + NE);               // NN+1
    int*   cursor    = row_start + (NN + 1);            // NN
    int*   deg       = cursor + NN;                     // NN
    int*   bsum      = deg + NN;                        // 512
    int*   start     = bsum + 512;                      // GNUM+1

    encoder_kernel<<<(NN + 3) / 4, 256, 0, stream>>>(
        x, ligW1, ligb1, ligW2, ligb2, protW1, protb1, protW2, protb2, h);
    bounds_kernel<<<2, 256, 0, stream>>>(batch, start);

    // ---- CSR build (once per launch) ----
    hipMemsetAsync(deg, 0, (size_t)NN * sizeof(int), stream);
    hist_kernel<<<(NE + 255) / 256, 256, 0, stream>>>(ei, deg);
    scan_a_kernel<<<NBLK_SCAN, 256, 0, stream>>>(deg, row_start, bsum);
    scan_b_kernel<<<1, 512, 0, stream>>>(bsum);
    scan_c_kernel<<<NBLK_SCAN, 256, 0, stream>>>(row_start, bsum, cursor);
    fill_kernel<<<(NE + 255) / 256, 256, 0, stream>>>(ei, cursor, perm);

    for (int l = 0; l < 3; ++l) {
        aggr_kernel<<<(NN + 3) / 4, 256, 0, stream>>>(
            row_start, perm, ea,
            convWe + (size_t)l * EDIM * H, convbe + (size_t)l * H, h, z);
        node_mlp_kernel<<<(NN + 3) / 4, 256, 0, stream>>>(
            z, convW1 + (size_t)l * H * H, convb1 + (size_t)l * H,
            convW2 + (size_t)l * H * H, convb2 + (size_t)l * H, h);
        graphnorm_kernel<<<GNUM, 256, 0, stream>>>(
            h, start, normw + (size_t)l * H, normb + (size_t)l * H, norma + (size_t)l * H);
    }
    final_kernel<<<GNUM, 256, 0, stream>>>(h, start, outW1, outb1, outW2, outb2, out);
}

// Round 4
// 1484.373 us; speedup vs baseline: 1.2661x; 1.0227x over previous
//
#include <hip/hip_runtime.h>

#define NN 100000   // nodes
#define NE 1600000  // edges
#define IN_CH 41
#define EDIM 8
#define H 64
#define GNUM 256
#define ATOM 21
#define EPSV 1e-5f

#define NBLK_SCAN ((NN + 255) / 256)   // 391

typedef unsigned short u16;
typedef unsigned int u32;

__device__ __forceinline__ float wave_reduce_sum(float v) {
#pragma unroll
    for (int o = 32; o > 0; o >>= 1) v += __shfl_xor(v, o, 64);
    return v;
}

__device__ __forceinline__ u16 f2bf(float f) {
    u32 u = __float_as_uint(f);
    u32 r = (u + 0x7FFFu + ((u >> 16) & 1u)) >> 16;   // RNE
    return (u16)r;
}
__device__ __forceinline__ float bf2f(u16 u) {
    return __uint_as_float(((u32)u) << 16);
}

// ---------------- encoder: h = select(mask, protMLP(x), ligMLP(x)) ----------
__global__ __launch_bounds__(256) void encoder_kernel(
    const float* __restrict__ x,
    const float* __restrict__ ligW1, const float* __restrict__ ligb1,
    const float* __restrict__ ligW2, const float* __restrict__ ligb2,
    const float* __restrict__ protW1, const float* __restrict__ protb1,
    const float* __restrict__ protW2, const float* __restrict__ protb2,
    float* __restrict__ h, u16* __restrict__ h16)
{
    const int lane = threadIdx.x & 63;
    const int node = blockIdx.x * 4 + (threadIdx.x >> 6);
    if (node >= NN) return;

    float xv = (lane < IN_CH) ? x[node * IN_CH + lane] : 0.0f;
    float m = (lane >= ATOM && lane < IN_CH) ? fabsf(xv) : 0.0f;
    m = wave_reduce_sum(m);
    const bool prot = m > 1e-6f;
    const float* W1 = prot ? protW1 : ligW1;
    const float* b1 = prot ? protb1 : ligb1;
    const float* W2 = prot ? protW2 : ligW2;
    const float* b2 = prot ? protb2 : ligb2;

    float acc = b1[lane];
#pragma unroll
    for (int d = 0; d < IN_CH; ++d)
        acc = fmaf(__shfl(xv, d, 64), W1[d * H + lane], acc);
    float h1 = fmaxf(acc, 0.0f);

    float acc2 = b2[lane];
#pragma unroll
    for (int d = 0; d < H; ++d)
        acc2 = fmaf(__shfl(h1, d, 64), W2[d * H + lane], acc2);
    float v = fmaxf(acc2, 0.0f);
    h[(size_t)node * H + lane] = v;
    h16[(size_t)node * H + lane] = f2bf(v);
}

// ---------------- per-graph node ranges (batch is sorted) -------------------
__global__ void bounds_kernel(const int* __restrict__ batch, int* __restrict__ start)
{
    int g = blockIdx.x * blockDim.x + threadIdx.x;
    if (g > GNUM) return;
    int lo = 0, hi = NN;
    while (lo < hi) {
        int mid = (lo + hi) >> 1;
        if (batch[mid] < g) lo = mid + 1; else hi = mid;
    }
    start[g] = lo;
}

// ---------------- CSR build ------------------------------------------------
__global__ __launch_bounds__(256) void hist_kernel(
    const int* __restrict__ ei, int* __restrict__ deg)
{
    int e = blockIdx.x * blockDim.x + threadIdx.x;
    if (e < NE) atomicAdd(&deg[ei[NE + e]], 1);
}

__global__ __launch_bounds__(256) void scan_a_kernel(
    const int* __restrict__ deg, int* __restrict__ row_start, int* __restrict__ bsum)
{
    __shared__ int s[256];
    const int t = threadIdx.x;
    const int idx = blockIdx.x * 256 + t;
    int v = (idx < NN) ? deg[idx] : 0;
    s[t] = v;
    __syncthreads();
#pragma unroll
    for (int off = 1; off < 256; off <<= 1) {
        int tmp = (t >= off) ? s[t - off] : 0;
        __syncthreads();
        s[t] += tmp;
        __syncthreads();
    }
    if (idx < NN) row_start[idx] = s[t] - v;  // exclusive
    if (t == 255) bsum[blockIdx.x] = s[255];
}

__global__ __launch_bounds__(512) void scan_b_kernel(int* __restrict__ bsum)
{
    __shared__ int s[512];
    const int t = threadIdx.x;
    int v = (t < NBLK_SCAN) ? bsum[t] : 0;
    s[t] = v;
    __syncthreads();
#pragma unroll
    for (int off = 1; off < 512; off <<= 1) {
        int tmp = (t >= off) ? s[t - off] : 0;
        __syncthreads();
        s[t] += tmp;
        __syncthreads();
    }
    if (t < NBLK_SCAN) bsum[t] = s[t] - v;  // exclusive
}

__global__ __launch_bounds__(256) void scan_c_kernel(
    int* __restrict__ row_start, const int* __restrict__ bsum, int* __restrict__ cursor)
{
    const int idx = blockIdx.x * 256 + threadIdx.x;
    if (idx < NN) {
        int rs = row_start[idx] + bsum[blockIdx.x];
        row_start[idx] = rs;
        cursor[idx] = rs;
    } else if (idx == NN) {
        row_start[NN] = NE;
    }
}

// fill: perm_src[pos] = src ; eab[pos] = bf16x8(edge_attr[e])
__global__ __launch_bounds__(256) void fill_kernel(
    const int* __restrict__ ei, const float* __restrict__ ea,
    int* __restrict__ cursor,
    int* __restrict__ perm_src, uint4* __restrict__ eab)
{
    int e = blockIdx.x * blockDim.x + threadIdx.x;
    if (e >= NE) return;
    int dst = ei[NE + e];
    int pos = atomicAdd(&cursor[dst], 1);
    perm_src[pos] = ei[e];
    const float4* e4 = (const float4*)(ea + (size_t)e * EDIM);
    float4 a = e4[0], b = e4[1];
    uint4 u;
    u.x = (u32)f2bf(a.x) | ((u32)f2bf(a.y) << 16);
    u.y = (u32)f2bf(a.z) | ((u32)f2bf(a.w) << 16);
    u.z = (u32)f2bf(b.x) | ((u32)f2bf(b.y) << 16);
    u.w = (u32)f2bf(b.z) | ((u32)f2bf(b.w) << 16);
    eab[pos] = u;
}

// ---- aggregation (in place): h[n] = h[n] + sum_{e->n} relu(bf16 h16[src]+lin(eab))
__global__ __launch_bounds__(256) void aggr_kernel(
    const int* __restrict__ row_start,
    const int* __restrict__ perm_src,
    const u16* __restrict__ eab,
    const float* __restrict__ We, const float* __restrict__ be,
    const u16* __restrict__ h16, float* __restrict__ h)
{
    const int lane = threadIdx.x & 63;
    const int node = blockIdx.x * 4 + (threadIdx.x >> 6);
    if (node >= NN) return;

    float we_r[EDIM];
#pragma unroll
    for (int d = 0; d < EDIM; ++d) we_r[d] = We[d * H + lane];
    const float be_r = be[lane];

    const int s = row_start[node];
    const int e = row_start[node + 1];
    float acc = h[(size_t)node * H + lane];

    for (int k0 = s; k0 < e; k0 += 8) {
        const int nk = e - k0;                      // >= 1
        // lanes 0..7 carry the 8 (clamped) source ids
        int sidx = k0 + (lane & 7);
        if (sidx > e - 1) sidx = e - 1;
        const int ps = perm_src[sidx];

        // lane reads channel (lane&7) of edge (lane>>3): 128B coalesced
        int eidx = k0 + (lane >> 3);
        if (eidx > e - 1) eidx = e - 1;
        const float eav = bf2f(eab[(size_t)eidx * EDIM + (lane & 7)]);

        float hv[8];
#pragma unroll
        for (int j = 0; j < 8; ++j) {
            const int src_j = __shfl(ps, j, 64);
            hv[j] = bf2f(h16[(size_t)src_j * H + lane]);
        }
#pragma unroll
        for (int j = 0; j < 8; ++j) {
            if (j < nk) {
                float msg = be_r;
#pragma unroll
                for (int d = 0; d < EDIM; ++d)
                    msg = fmaf(__shfl(eav, j * 8 + d, 64), we_r[d], msg);
                acc += fmaxf(hv[j] + msg, 0.0f);
            }
        }
    }
    h[(size_t)node * H + lane] = acc;
}

// ---------------- node MLP (in place): h = relu(h@W1+b1)@W2+b2 --------------
__global__ __launch_bounds__(256) void node_mlp_kernel(
    const float* __restrict__ W1, const float* __restrict__ b1,
    const float* __restrict__ W2, const float* __restrict__ b2,
    float* __restrict__ h)
{
    const int lane = threadIdx.x & 63;
    const int node = blockIdx.x * 4 + (threadIdx.x >> 6);
    if (node >= NN) return;
    float zv = h[(size_t)node * H + lane];
    float acc = b1[lane];
#pragma unroll
    for (int d = 0; d < H; ++d)
        acc = fmaf(__shfl(zv, d, 64), W1[d * H + lane], acc);
    float t = fmaxf(acc, 0.0f);
    float acc2 = b2[lane];
#pragma unroll
    for (int d = 0; d < H; ++d)
        acc2 = fmaf(__shfl(t, d, 64), W2[d * H + lane], acc2);
    h[(size_t)node * H + lane] = acc2;
}

// ------- GraphNorm + relu, in place; also refresh bf16 mirror ---------------
__global__ __launch_bounds__(256) void graphnorm_kernel(
    float* __restrict__ h, u16* __restrict__ h16,
    const int* __restrict__ start,
    const float* __restrict__ w, const float* __restrict__ b,
    const float* __restrict__ a)
{
    __shared__ float red1[4][H], red2[4][H];
    __shared__ float amean_s[H], rstd_s[H];
    const int g = blockIdx.x;
    const int lane = threadIdx.x & 63;
    const int wv = threadIdx.x >> 6;
    const int s = start[g], e = start[g + 1];

    float s1 = 0.f, s2 = 0.f;
    for (int i = s + wv; i < e; i += 4) {
        float v = h[(size_t)i * H + lane];
        s1 += v; s2 += v * v;
    }
    red1[wv][lane] = s1; red2[wv][lane] = s2;
    __syncthreads();
    if (threadIdx.x < H) {
        float t1 = red1[0][lane] + red1[1][lane] + red1[2][lane] + red1[3][lane];
        float t2 = red2[0][lane] + red2[1][lane] + red2[2][lane] + red2[3][lane];
        float cnt = fmaxf((float)(e - s), 1.0f);
        float mean = t1 / cnt;
        float alpha = a[lane];
        float var = t2 / cnt - (2.0f * alpha - alpha * alpha) * mean * mean;
        var = fmaxf(var, 0.0f);
        amean_s[lane] = alpha * mean;
        rstd_s[lane] = rsqrtf(var + EPSV);
    }
    __syncthreads();
    const float am = amean_s[lane], rstd = rstd_s[lane];
    const float ww = w[lane], bb = b[lane];
    for (int i = s + wv; i < e; i += 4) {
        float v = (h[(size_t)i * H + lane] - am) * rstd * ww + bb;
        v = fmaxf(v, 0.0f);
        h[(size_t)i * H + lane] = v;
        h16[(size_t)i * H + lane] = f2bf(v);
    }
}

// ---------------- pool + readout: out[g] ------------------------------------
__global__ __launch_bounds__(256) void final_kernel(
    const float* __restrict__ h, const int* __restrict__ start,
    const float* __restrict__ W1, const float* __restrict__ b1,
    const float* __restrict__ W2, const float* __restrict__ b2,
    float* __restrict__ out)
{
    __shared__ float red[4][H];
    __shared__ float g_s[H];
    const int g = blockIdx.x;
    const int lane = threadIdx.x & 63;
    const int wv = threadIdx.x >> 6;
    const int s = start[g], e = start[g + 1];

    float s1 = 0.f;
    for (int i = s + wv; i < e; i += 4) s1 += h[(size_t)i * H + lane];
    red[wv][lane] = s1;
    __syncthreads();
    if (threadIdx.x < H)
        g_s[lane] = red[0][lane] + red[1][lane] + red[2][lane] + red[3][lane];
    __syncthreads();
    if (threadIdx.x < H) {
        float acc = b1[lane];
#pragma unroll
        for (int d = 0; d < H; ++d)
            acc = fmaf(g_s[d], W1[d * H + lane], acc);
        float r = fmaxf(acc, 0.0f);
        float v = r * W2[lane];
        v = wave_reduce_sum(v);
        if (lane == 0) out[g] = v + b2[0];
    }
}

extern "C" void kernel_launch(void* const* d_in, const int* in_sizes, int n_in,
                              void* d_out, int out_size, void* d_ws, size_t ws_size,
                              hipStream_t stream)
{
    const float* x      = (const float*)d_in[0];
    const int*   ei     = (const int*)  d_in[1];
    const float* ea     = (const float*)d_in[2];
    const int*   batch  = (const int*)  d_in[3];
    const float* ligW1  = (const float*)d_in[4];
    const float* ligb1  = (const float*)d_in[5];
    const float* ligW2  = (const float*)d_in[6];
    const float* ligb2  = (const float*)d_in[7];
    const float* protW1 = (const float*)d_in[8];
    const float* protb1 = (const float*)d_in[9];
    const float* protW2 = (const float*)d_in[10];
    const float* protb2 = (const float*)d_in[11];
    const float* convWe = (const float*)d_in[12];
    const float* convbe = (const float*)d_in[13];
    const float* convW1 = (const float*)d_in[14];
    const float* convb1 = (const float*)d_in[15];
    const float* convW2 = (const float*)d_in[16];
    const float* convb2 = (const float*)d_in[17];
    const float* normw  = (const float*)d_in[18];
    const float* normb  = (const float*)d_in[19];
    const float* norma  = (const float*)d_in[20];
    const float* outW1  = (const float*)d_in[21];
    const float* outb1  = (const float*)d_in[22];
    const float* outW2  = (const float*)d_in[23];
    const float* outb2  = (const float*)d_in[24];

    float* out = (float*)d_out;

    // workspace layout (16B-aligned blocks first)
    float* h         = (float*)d_ws;                    // NN*H f32      25.6 MB
    uint4* eab       = (uint4*)(h + (size_t)NN * H);    // NE uint4      25.6 MB
    u16*   h16       = (u16*)(eab + (size_t)NE);        // NN*H u16      12.8 MB
    int*   perm_src  = (int*)(h16 + (size_t)NN * H);    // NE             6.4 MB
    int*   row_start = perm_src + NE;                   // NN+1
    int*   cursor    = row_start + (NN + 1);            // NN
    int*   deg       = cursor + NN;                     // NN
    int*   bsum      = deg + NN;                        // 512
    int*   start     = bsum + 512;                      // GNUM+1

    encoder_kernel<<<(NN + 3) / 4, 256, 0, stream>>>(
        x, ligW1, ligb1, ligW2, ligb2, protW1, protb1, protW2, protb2, h, h16);
    bounds_kernel<<<2, 256, 0, stream>>>(batch, start);

    // ---- CSR build (once per launch) ----
    hipMemsetAsync(deg, 0, (size_t)NN * sizeof(int), stream);
    hist_kernel<<<(NE + 255) / 256, 256, 0, stream>>>(ei, deg);
    scan_a_kernel<<<NBLK_SCAN, 256, 0, stream>>>(deg, row_start, bsum);
    scan_b_kernel<<<1, 512, 0, stream>>>(bsum);
    scan_c_kernel<<<NBLK_SCAN, 256, 0, stream>>>(row_start, bsum, cursor);
    fill_kernel<<<(NE + 255) / 256, 256, 0, stream>>>(ei, ea, cursor, perm_src, eab);

    for (int l = 0; l < 3; ++l) {
        aggr_kernel<<<(NN + 3) / 4, 256, 0, stream>>>(
            row_start, perm_src, (const u16*)eab,
            convWe + (size_t)l * EDIM * H, convbe + (size_t)l * H, h16, h);
        node_mlp_kernel<<<(NN + 3) / 4, 256, 0, stream>>>(
            convW1 + (size_t)l * H * H, convb1 + (size_t)l * H,
            convW2 + (size_t)l * H * H, convb2 + (size_t)l * H, h);
        graphnorm_kernel<<<GNUM, 256, 0, stream>>>(
            h, h16, start, normw + (size_t)l * H, normb + (size_t)l * H, norma + (size_t)l * H);
    }
    final_kernel<<<GNUM, 256, 0, stream>>>(h, start, outW1, outb1, outW2, outb2, out);
}

// Round 5
// 938.406 us; speedup vs baseline: 2.0027x; 1.5818x over previous
//
#include <hip/hip_runtime.h>

#define NN 100000   // nodes
#define NE 1600000  // edges
#define IN_CH 41
#define EDIM 8
#define H 64
#define GNUM 256
#define ATOM 21
#define EPSV 1e-5f
#define EPW 16      // edges per wave in aggr (NE % EPW == 0)
#define MLPB 64     // threads per block in node_mlp (1 wave)

#define NBLK_SCAN ((NN + 255) / 256)   // 391

typedef unsigned short u16;
typedef unsigned int u32;

__device__ __forceinline__ float wave_reduce_sum(float v) {
#pragma unroll
    for (int o = 32; o > 0; o >>= 1) v += __shfl_xor(v, o, 64);
    return v;
}

__device__ __forceinline__ u16 f2bf(float f) {
    u32 u = __float_as_uint(f);
    u32 r = (u + 0x7FFFu + ((u >> 16) & 1u)) >> 16;   // RNE
    return (u16)r;
}
__device__ __forceinline__ float bf2f(u16 u) {
    return __uint_as_float(((u32)u) << 16);
}

// ---------------- encoder: h = select(mask, protMLP(x), ligMLP(x)) ----------
__global__ __launch_bounds__(256) void encoder_kernel(
    const float* __restrict__ x,
    const float* __restrict__ ligW1, const float* __restrict__ ligb1,
    const float* __restrict__ ligW2, const float* __restrict__ ligb2,
    const float* __restrict__ protW1, const float* __restrict__ protb1,
    const float* __restrict__ protW2, const float* __restrict__ protb2,
    float* __restrict__ h, u16* __restrict__ h16)
{
    const int lane = threadIdx.x & 63;
    const int node = blockIdx.x * 4 + (threadIdx.x >> 6);
    if (node >= NN) return;

    float xv = (lane < IN_CH) ? x[node * IN_CH + lane] : 0.0f;
    float m = (lane >= ATOM && lane < IN_CH) ? fabsf(xv) : 0.0f;
    m = wave_reduce_sum(m);
    const bool prot = m > 1e-6f;
    const float* W1 = prot ? protW1 : ligW1;
    const float* b1 = prot ? protb1 : ligb1;
    const float* W2 = prot ? protW2 : ligW2;
    const float* b2 = prot ? protb2 : ligb2;

    float acc = b1[lane];
#pragma unroll
    for (int d = 0; d < IN_CH; ++d)
        acc = fmaf(__shfl(xv, d, 64), W1[d * H + lane], acc);
    float h1 = fmaxf(acc, 0.0f);

    float acc2 = b2[lane];
#pragma unroll
    for (int d = 0; d < H; ++d)
        acc2 = fmaf(__shfl(h1, d, 64), W2[d * H + lane], acc2);
    float v = fmaxf(acc2, 0.0f);
    h[(size_t)node * H + lane] = v;
    h16[(size_t)node * H + lane] = f2bf(v);
}

// ---------------- per-graph node ranges (batch is sorted) -------------------
__global__ void bounds_kernel(const int* __restrict__ batch, int* __restrict__ start)
{
    int g = blockIdx.x * blockDim.x + threadIdx.x;
    if (g > GNUM) return;
    int lo = 0, hi = NN;
    while (lo < hi) {
        int mid = (lo + hi) >> 1;
        if (batch[mid] < g) lo = mid + 1; else hi = mid;
    }
    start[g] = lo;
}

// ---------------- CSR build ------------------------------------------------
__global__ __launch_bounds__(256) void hist_kernel(
    const int* __restrict__ ei, int* __restrict__ deg)
{
    int e = blockIdx.x * blockDim.x + threadIdx.x;
    if (e < NE) atomicAdd(&deg[ei[NE + e]], 1);
}

__global__ __launch_bounds__(256) void scan_a_kernel(
    const int* __restrict__ deg, int* __restrict__ row_start, int* __restrict__ bsum)
{
    __shared__ int s[256];
    const int t = threadIdx.x;
    const int idx = blockIdx.x * 256 + t;
    int v = (idx < NN) ? deg[idx] : 0;
    s[t] = v;
    __syncthreads();
#pragma unroll
    for (int off = 1; off < 256; off <<= 1) {
        int tmp = (t >= off) ? s[t - off] : 0;
        __syncthreads();
        s[t] += tmp;
        __syncthreads();
    }
    if (idx < NN) row_start[idx] = s[t] - v;  // exclusive
    if (t == 255) bsum[blockIdx.x] = s[255];
}

__global__ __launch_bounds__(512) void scan_b_kernel(int* __restrict__ bsum)
{
    __shared__ int s[512];
    const int t = threadIdx.x;
    int v = (t < NBLK_SCAN) ? bsum[t] : 0;
    s[t] = v;
    __syncthreads();
#pragma unroll
    for (int off = 1; off < 512; off <<= 1) {
        int tmp = (t >= off) ? s[t - off] : 0;
        __syncthreads();
        s[t] += tmp;
        __syncthreads();
    }
    if (t < NBLK_SCAN) bsum[t] = s[t] - v;  // exclusive
}

__global__ __launch_bounds__(256) void scan_c_kernel(
    int* __restrict__ row_start, const int* __restrict__ bsum, int* __restrict__ cursor)
{
    const int idx = blockIdx.x * 256 + threadIdx.x;
    if (idx < NN) {
        int rs = row_start[idx] + bsum[blockIdx.x];
        row_start[idx] = rs;
        cursor[idx] = rs;
    } else if (idx == NN) {
        row_start[NN] = NE;
    }
}

// fill: perm2[pos] = (src,dst) ; eab[pos] = bf16x8(edge_attr[e])
__global__ __launch_bounds__(256) void fill_kernel(
    const int* __restrict__ ei, const float* __restrict__ ea,
    int* __restrict__ cursor,
    int2* __restrict__ perm2, uint4* __restrict__ eab)
{
    int e = blockIdx.x * blockDim.x + threadIdx.x;
    if (e >= NE) return;
    int src = ei[e];
    int dst = ei[NE + e];
    int pos = atomicAdd(&cursor[dst], 1);
    perm2[pos] = make_int2(src, dst);
    const float4* e4 = (const float4*)(ea + (size_t)e * EDIM);
    float4 a = e4[0], b = e4[1];
    uint4 u;
    u.x = (u32)f2bf(a.x) | ((u32)f2bf(a.y) << 16);
    u.y = (u32)f2bf(a.z) | ((u32)f2bf(a.w) << 16);
    u.z = (u32)f2bf(b.x) | ((u32)f2bf(b.y) << 16);
    u.w = (u32)f2bf(b.z) | ((u32)f2bf(b.w) << 16);
    eab[pos] = u;
}

// ---- edge-centric aggregation: one wave per 16 consecutive CSR edges -------
// h[dst] += sum relu(h16[src] + ea@We + be), segmented by dst (contiguous),
// flushed via unsafeAtomicAdd. h already holds the self term.
__global__ __launch_bounds__(256) void aggr_kernel(
    const int2* __restrict__ perm2,
    const u32* __restrict__ eab32,
    const float* __restrict__ We, const float* __restrict__ be,
    const u16* __restrict__ h16, float* __restrict__ h)
{
    const int lane = threadIdx.x & 63;
    const int chunk = blockIdx.x * 4 + (threadIdx.x >> 6);
    const int base = chunk * EPW;

    float we_r[EDIM];
#pragma unroll
    for (int d = 0; d < EDIM; ++d) we_r[d] = We[d * H + lane];
    const float be_r = be[lane];

    // lanes 0..15 carry the 16 (src,dst) pairs (upper lanes broadcast-load)
    const int2 pd = perm2[base + (lane & 15)];
    // lane l holds channel-pair (l&3) of edge (l>>2): 256B coalesced
    const u32 eu = eab32[(size_t)base * 4 + lane];

    float hv[EPW];
#pragma unroll
    for (int j = 0; j < EPW; ++j) {
        const int sj = __builtin_amdgcn_readlane(pd.x, j);
        hv[j] = bf2f(h16[(size_t)sj * H + lane]);
    }

    float acc = 0.0f;
    int cur = __builtin_amdgcn_readlane(pd.y, 0);
#pragma unroll
    for (int j = 0; j < EPW; ++j) {
        const int dj = __builtin_amdgcn_readlane(pd.y, j);
        float msg = be_r;
#pragma unroll
        for (int p = 0; p < 4; ++p) {
            const u32 w2 = __builtin_amdgcn_readlane(eu, j * 4 + p);
            msg = fmaf(__uint_as_float(w2 << 16), we_r[2 * p], msg);
            msg = fmaf(__uint_as_float(w2 & 0xffff0000u), we_r[2 * p + 1], msg);
        }
        if (dj != cur) {                       // wave-uniform branch
            unsafeAtomicAdd(&h[(size_t)cur * H + lane], acc);
            acc = 0.0f;
            cur = dj;
        }
        acc += fmaxf(hv[j] + msg, 0.0f);
    }
    unsafeAtomicAdd(&h[(size_t)cur * H + lane], acc);
}

// ---------------- node MLP (in place): thread-per-node, scalar weights ------
__global__ __launch_bounds__(MLPB) void node_mlp_kernel(
    const float* __restrict__ W1, const float* __restrict__ b1,
    const float* __restrict__ W2, const float* __restrict__ b2,
    float* __restrict__ h)
{
    __shared__ float ts[MLPB * 65];
    const int t = threadIdx.x;
    const int n = blockIdx.x * MLPB + t;
    if (n >= NN) return;
    float* hrow = h + (size_t)n * H;

    float acc[H];
#pragma unroll
    for (int d = 0; d < H; ++d) acc[d] = b1[d];
    for (int k4 = 0; k4 < H / 4; ++k4) {
        const float4 zc = ((const float4*)hrow)[k4];
        const float* w = W1 + (size_t)k4 * 4 * H;
#pragma unroll
        for (int d = 0; d < H; ++d) acc[d] = fmaf(zc.x, w[d], acc[d]);
#pragma unroll
        for (int d = 0; d < H; ++d) acc[d] = fmaf(zc.y, w[H + d], acc[d]);
#pragma unroll
        for (int d = 0; d < H; ++d) acc[d] = fmaf(zc.z, w[2 * H + d], acc[d]);
#pragma unroll
        for (int d = 0; d < H; ++d) acc[d] = fmaf(zc.w, w[3 * H + d], acc[d]);
    }
    // stash relu(hidden) in own LDS row (no cross-thread sharing -> no barrier)
#pragma unroll
    for (int d = 0; d < H; ++d) ts[t * 65 + d] = fmaxf(acc[d], 0.0f);

#pragma unroll
    for (int d = 0; d < H; ++d) acc[d] = b2[d];
    for (int k4 = 0; k4 < H / 4; ++k4) {
        const float* w = W2 + (size_t)k4 * 4 * H;
        const float z0 = ts[t * 65 + k4 * 4 + 0];
        const float z1 = ts[t * 65 + k4 * 4 + 1];
        const float z2 = ts[t * 65 + k4 * 4 + 2];
        const float z3 = ts[t * 65 + k4 * 4 + 3];
#pragma unroll
        for (int d = 0; d < H; ++d) acc[d] = fmaf(z0, w[d], acc[d]);
#pragma unroll
        for (int d = 0; d < H; ++d) acc[d] = fmaf(z1, w[H + d], acc[d]);
#pragma unroll
        for (int d = 0; d < H; ++d) acc[d] = fmaf(z2, w[2 * H + d], acc[d]);
#pragma unroll
        for (int d = 0; d < H; ++d) acc[d] = fmaf(z3, w[3 * H + d], acc[d]);
    }
#pragma unroll
    for (int d4 = 0; d4 < H / 4; ++d4)
        ((float4*)hrow)[d4] = make_float4(acc[4 * d4], acc[4 * d4 + 1],
                                          acc[4 * d4 + 2], acc[4 * d4 + 3]);
}

// ------- GraphNorm + relu, in place; also refresh bf16 mirror ---------------
__global__ __launch_bounds__(256) void graphnorm_kernel(
    float* __restrict__ h, u16* __restrict__ h16,
    const int* __restrict__ start,
    const float* __restrict__ w, const float* __restrict__ b,
    const float* __restrict__ a)
{
    __shared__ float red1[4][H], red2[4][H];
    __shared__ float amean_s[H], rstd_s[H];
    const int g = blockIdx.x;
    const int lane = threadIdx.x & 63;
    const int wv = threadIdx.x >> 6;
    const int s = start[g], e = start[g + 1];

    float s1 = 0.f, s2 = 0.f;
    for (int i = s + wv; i < e; i += 4) {
        float v = h[(size_t)i * H + lane];
        s1 += v; s2 += v * v;
    }
    red1[wv][lane] = s1; red2[wv][lane] = s2;
    __syncthreads();
    if (threadIdx.x < H) {
        float t1 = red1[0][lane] + red1[1][lane] + red1[2][lane] + red1[3][lane];
        float t2 = red2[0][lane] + red2[1][lane] + red2[2][lane] + red2[3][lane];
        float cnt = fmaxf((float)(e - s), 1.0f);
        float mean = t1 / cnt;
        float alpha = a[lane];
        float var = t2 / cnt - (2.0f * alpha - alpha * alpha) * mean * mean;
        var = fmaxf(var, 0.0f);
        amean_s[lane] = alpha * mean;
        rstd_s[lane] = rsqrtf(var + EPSV);
    }
    __syncthreads();
    const float am = amean_s[lane], rstd = rstd_s[lane];
    const float ww = w[lane], bb = b[lane];
    for (int i = s + wv; i < e; i += 4) {
        float v = (h[(size_t)i * H + lane] - am) * rstd * ww + bb;
        v = fmaxf(v, 0.0f);
        h[(size_t)i * H + lane] = v;
        h16[(size_t)i * H + lane] = f2bf(v);
    }
}

// ---------------- pool + readout: out[g] ------------------------------------
__global__ __launch_bounds__(256) void final_kernel(
    const float* __restrict__ h, const int* __restrict__ start,
    const float* __restrict__ W1, const float* __restrict__ b1,
    const float* __restrict__ W2, const float* __restrict__ b2,
    float* __restrict__ out)
{
    __shared__ float red[4][H];
    __shared__ float g_s[H];
    const int g = blockIdx.x;
    const int lane = threadIdx.x & 63;
    const int wv = threadIdx.x >> 6;
    const int s = start[g], e = start[g + 1];

    float s1 = 0.f;
    for (int i = s + wv; i < e; i += 4) s1 += h[(size_t)i * H + lane];
    red[wv][lane] = s1;
    __syncthreads();
    if (threadIdx.x < H)
        g_s[lane] = red[0][lane] + red[1][lane] + red[2][lane] + red[3][lane];
    __syncthreads();
    if (threadIdx.x < H) {
        float acc = b1[lane];
#pragma unroll
        for (int d = 0; d < H; ++d)
            acc = fmaf(g_s[d], W1[d * H + lane], acc);
        float r = fmaxf(acc, 0.0f);
        float v = r * W2[lane];
        v = wave_reduce_sum(v);
        if (lane == 0) out[g] = v + b2[0];
    }
}

extern "C" void kernel_launch(void* const* d_in, const int* in_sizes, int n_in,
                              void* d_out, int out_size, void* d_ws, size_t ws_size,
                              hipStream_t stream)
{
    const float* x      = (const float*)d_in[0];
    const int*   ei     = (const int*)  d_in[1];
    const float* ea     = (const float*)d_in[2];
    const int*   batch  = (const int*)  d_in[3];
    const float* ligW1  = (const float*)d_in[4];
    const float* ligb1  = (const float*)d_in[5];
    const float* ligW2  = (const float*)d_in[6];
    const float* ligb2  = (const float*)d_in[7];
    const float* protW1 = (const float*)d_in[8];
    const float* protb1 = (const float*)d_in[9];
    const float* protW2 = (const float*)d_in[10];
    const float* protb2 = (const float*)d_in[11];
    const float* convWe = (const float*)d_in[12];
    const float* convbe = (const float*)d_in[13];
    const float* convW1 = (const float*)d_in[14];
    const float* convb1 = (const float*)d_in[15];
    const float* convW2 = (const float*)d_in[16];
    const float* convb2 = (const float*)d_in[17];
    const float* normw  = (const float*)d_in[18];
    const float* normb  = (const float*)d_in[19];
    const float* norma  = (const float*)d_in[20];
    const float* outW1  = (const float*)d_in[21];
    const float* outb1  = (const float*)d_in[22];
    const float* outW2  = (const float*)d_in[23];
    const float* outb2  = (const float*)d_in[24];

    float* out = (float*)d_out;

    // workspace layout (16B-aligned blocks first)
    float* h         = (float*)d_ws;                    // NN*H f32      25.6 MB
    uint4* eab       = (uint4*)(h + (size_t)NN * H);    // NE uint4      25.6 MB
    int2*  perm2     = (int2*)(eab + (size_t)NE);       // NE int2       12.8 MB
    u16*   h16       = (u16*)(perm2 + (size_t)NE);      // NN*H u16      12.8 MB
    int*   row_start = (int*)(h16 + (size_t)NN * H);    // NN+1
    int*   cursor    = row_start + (NN + 1);            // NN
    int*   deg       = cursor + NN;                     // NN
    int*   bsum      = deg + NN;                        // 512
    int*   start     = bsum + 512;                      // GNUM+1

    encoder_kernel<<<(NN + 3) / 4, 256, 0, stream>>>(
        x, ligW1, ligb1, ligW2, ligb2, protW1, protb1, protW2, protb2, h, h16);
    bounds_kernel<<<2, 256, 0, stream>>>(batch, start);

    // ---- CSR build (once per launch) ----
    hipMemsetAsync(deg, 0, (size_t)NN * sizeof(int), stream);
    hist_kernel<<<(NE + 255) / 256, 256, 0, stream>>>(ei, deg);
    scan_a_kernel<<<NBLK_SCAN, 256, 0, stream>>>(deg, row_start, bsum);
    scan_b_kernel<<<1, 512, 0, stream>>>(bsum);
    scan_c_kernel<<<NBLK_SCAN, 256, 0, stream>>>(row_start, bsum, cursor);
    fill_kernel<<<(NE + 255) / 256, 256, 0, stream>>>(ei, ea, cursor, perm2, eab);

    const int aggr_blocks = NE / EPW / 4;   // 25000, exact
    const int mlp_blocks = (NN + MLPB - 1) / MLPB;
    for (int l = 0; l < 3; ++l) {
        aggr_kernel<<<aggr_blocks, 256, 0, stream>>>(
            perm2, (const u32*)eab,
            convWe + (size_t)l * EDIM * H, convbe + (size_t)l * H, h16, h);
        node_mlp_kernel<<<mlp_blocks, MLPB, 0, stream>>>(
            convW1 + (size_t)l * H * H, convb1 + (size_t)l * H,
            convW2 + (size_t)l * H * H, convb2 + (size_t)l * H, h);
        graphnorm_kernel<<<GNUM, 256, 0, stream>>>(
            h, h16, start, normw + (size_t)l * H, normb + (size_t)l * H, norma + (size_t)l * H);
    }
    final_kernel<<<GNUM, 256, 0, stream>>>(h, start, outW1, outb1, outW2, outb2, out);
}